// Round 2
// baseline (65.593 us; speedup 1.0000x reference)
//
#include <hip/hip_runtime.h>

// B=16384, K=32, D=128, N_ENT=100000, N_REL=64
// inputs: 0 user_emb f32[B,D], 1 entity_ids i32[B], 2 neigh_ent_ids i32[B,K],
//         3 neigh_rel_ids i32[B,K], 4 entity_table f32[N_ENT,D],
//         5 relation_table f32[N_REL,D], 6 W f32[D,D]
// out: f32[B,D]

#define BB 16384
#define KK 32
#define DD 128
#define NREL 64

// Mt[d][r] = sum_e rel[r,e] * W[e,d]   ((rel @ W)^T), 128x64 f32 = 32KB
__global__ void kgnn_precompute_mt(const float* __restrict__ rel,
                                   const float* __restrict__ W,
                                   float* __restrict__ Mt) {
    const int r = blockIdx.x;   // 0..63
    const int d = threadIdx.x;  // 0..127
    float acc = 0.f;
#pragma unroll 8
    for (int e = 0; e < DD; ++e) {
        acc += rel[r * DD + e] * W[e * DD + d];
    }
    Mt[d * NREL + r] = acc;
}

// all_scores[b][r] = u[b] . M[r]  for all 64 relations (cheap VALU kernel)
__global__ __launch_bounds__(256) void kgnn_scores(
    const float* __restrict__ user_emb,
    const float* __restrict__ Mt,          // [d][r]
    float* __restrict__ all_scores) {      // [B][NREL]
    __shared__ float m_lds[DD * NREL];     // 32 KB
    __shared__ float u_lds[4][DD];

    const int tid = threadIdx.x;
    {
        const float4* src = (const float4*)Mt;
        float4* dst = (float4*)m_lds;
#pragma unroll
        for (int i = 0; i < 8; ++i) dst[tid + 256 * i] = src[tid + 256 * i];
    }
    const int wave = tid >> 6;
    const int lane = tid & 63;
    const int row = blockIdx.x * 4 + wave;
    {
        float2 u2 = ((const float2*)(user_emb + row * DD))[lane];
        u_lds[wave][2 * lane] = u2.x;
        u_lds[wave][2 * lane + 1] = u2.y;
    }
    __syncthreads();

    // lane = relation id (0..63). bank = lane%32 -> 2-way (free); u_lds broadcast.
    float acc = 0.f;
#pragma unroll 8
    for (int d = 0; d < DD; ++d) {
        acc = fmaf(u_lds[wave][d], m_lds[d * NREL + lane], acc);
    }
    all_scores[row * NREL + lane] = acc;
}

// Hot kernel: pure gather + softmax + weighted sum. No LDS -> high occupancy.
__global__ __launch_bounds__(256, 8) void kgnn_agg(
    const int* __restrict__ entity_ids,
    const int* __restrict__ neigh_ent,
    const int* __restrict__ neigh_rel,
    const float* __restrict__ entity_table,
    const float* __restrict__ all_scores,
    float* __restrict__ out) {
    const int tid = threadIdx.x;
    const int wave = tid >> 6;
    const int lane = tid & 63;
    const int row = blockIdx.x * 4 + wave;
    const int k = lane & 31;

    const int rid = neigh_rel[row * KK + k];
    const int eid = neigh_ent[row * KK + k];
    const int se = entity_ids[row];

    // issue self-row load early to overlap with softmax
    const float2 s2 = ((const float2*)(entity_table + (long long)se * DD))[lane];

    float p = all_scores[row * NREL + rid];  // 256B row, L2-hot

    // softmax over k (halves hold identical copies; xor masks <32 stay in-half)
    float mx = p;
#pragma unroll
    for (int m = 16; m >= 1; m >>= 1) mx = fmaxf(mx, __shfl_xor(mx, m));
    float w = __expf(p - mx);
    float s = w;
#pragma unroll
    for (int m = 16; m >= 1; m >>= 1) s += __shfl_xor(s, m);
    w /= s;

    // weighted gather-sum: lane owns 2 dims; unroll 8 keeps 8 rows in flight
    float2 acc = {0.f, 0.f};
#pragma unroll 8
    for (int kk2 = 0; kk2 < KK; ++kk2) {
        const float wk = __shfl(w, kk2);
        const int ek = __shfl(eid, kk2);
        const float2 e2 = ((const float2*)(entity_table + (long long)ek * DD))[lane];
        acc.x = fmaf(wk, e2.x, acc.x);
        acc.y = fmaf(wk, e2.y, acc.y);
    }

    float2 o;
    o.x = fmaxf(0.f, s2.x + acc.x);
    o.y = fmaxf(0.f, s2.y + acc.y);
    ((float2*)(out + (long long)row * DD))[lane] = o;
}

extern "C" void kernel_launch(void* const* d_in, const int* in_sizes, int n_in,
                              void* d_out, int out_size, void* d_ws, size_t ws_size,
                              hipStream_t stream) {
    const float* user_emb = (const float*)d_in[0];
    const int* entity_ids = (const int*)d_in[1];
    const int* neigh_ent = (const int*)d_in[2];
    const int* neigh_rel = (const int*)d_in[3];
    const float* entity_table = (const float*)d_in[4];
    const float* relation_table = (const float*)d_in[5];
    const float* W = (const float*)d_in[6];
    float* out = (float*)d_out;

    float* Mt = (float*)d_ws;                       // 32 KB
    float* all_scores = (float*)d_ws + DD * NREL;   // 4.2 MB

    kgnn_precompute_mt<<<NREL, DD, 0, stream>>>(relation_table, W, Mt);
    kgnn_scores<<<BB / 4, 256, 0, stream>>>(user_emb, Mt, all_scores);
    kgnn_agg<<<BB / 4, 256, 0, stream>>>(entity_ids, neigh_ent, neigh_rel,
                                         entity_table, all_scores, out);
}